// Round 1
// baseline (342.023 us; speedup 1.0000x reference)
//
#include <hip/hip_runtime.h>
#include <cstdint>
#include <cstddef>

#define BQ 16
#define NT 1024
#define CH 768
#define HIDN 128
#define OUTF 2304
#define MTOT (BQ*NT)   // 16384 tokens

typedef __attribute__((ext_vector_type(4))) float f32x4;
typedef __attribute__((ext_vector_type(8))) short short8;   // 8 x bf16 payload

// ---------- small helpers ----------
__device__ __forceinline__ unsigned short f2bf(float f){
  unsigned u = __float_as_uint(f);
  u += 0x7FFFu + ((u >> 16) & 1u);      // RNE
  return (unsigned short)(u >> 16);
}
__device__ __forceinline__ float bf2f(unsigned short h){
  return __uint_as_float(((unsigned)h) << 16);
}

__device__ __forceinline__ void gload16(const void* g, void* l){
  // async global->LDS, 16B per lane; LDS dest is wave-uniform base + lane*16
  __builtin_amdgcn_global_load_lds((const __attribute__((address_space(1))) void*)g,
                                   (__attribute__((address_space(3))) void*)l, 16, 0, 0);
}

__device__ __forceinline__ void mfma16(f32x4& d, short8 a, short8 b){
  asm volatile("v_mfma_f32_16x16x32_bf16 %0, %1, %2, %0" : "+v"(d) : "v"(a), "v"(b));
}

// ---------- fp32 -> bf16 convert ----------
__global__ void k_f2bf(const float* __restrict__ src, unsigned short* __restrict__ dst, int n){
  int i = (blockIdx.x * blockDim.x + threadIdx.x) * 4;
  if (i + 3 >= n) { for (int j = i; j < n; ++j) dst[j] = f2bf(src[j]); return; }
  float4 v = *reinterpret_cast<const float4*>(src + i);
  ushort4 o;
  o.x = f2bf(v.x); o.y = f2bf(v.y); o.z = f2bf(v.z); o.w = f2bf(v.w);
  *reinterpret_cast<ushort4*>(dst + i) = o;
}

// ---------- per-batch token mean of `input` + ||mean||^2 ----------
__global__ void k_mean(const float* __restrict__ input, float* __restrict__ meanb,
                       float* __restrict__ n1sq){
  int b = blockIdx.x, cg = blockIdx.y;
  int tid = threadIdx.x;
  int h = tid >> 7, cl = tid & 127;
  int c = cg * 128 + cl;
  const float* ip = input + (size_t)b*NT*CH + (size_t)h*512*CH + c;
  float s = 0.f;
  #pragma unroll 4
  for (int n = 0; n < 512; ++n) s += ip[(size_t)n*CH];
  __shared__ float tmp[256];
  tmp[tid] = s; __syncthreads();
  if (tid < 128){
    float m = (tmp[tid] + tmp[tid+128]) * (1.0f/1024.0f);
    meanb[b*CH + cg*128 + tid] = m;
    float q = m * m;
    for (int off = 32; off; off >>= 1) q += __shfl_down(q, off, 64);
    if ((tid & 63) == 0) atomicAdd(&n1sq[b], q);
  }
}

// ---------- MFMA GEMM: C[M,N] = A[M,K](bf16) * B[N,K]^T(bf16), m97 structure ----------
// EPI 0: Cf = acc + bias (f32 out). EPI 1: Cb = bf16(acc + bias + add) (bf16 out).
template<int EPI>
__global__ __launch_bounds__(256, 2)
void k_gemm(const unsigned short* __restrict__ A, const unsigned short* __restrict__ B,
            const float* __restrict__ bias, const float* __restrict__ add,
            float* __restrict__ Cf, unsigned short* __restrict__ Cb,
            int M, int N, int K)
{
  __shared__ unsigned short sA[128][32];
  __shared__ unsigned short sB[128][32];
  const int tid = threadIdx.x;
  const int wv = tid >> 6, ln = tid & 63;
  const int wr = wv >> 1, wc = wv & 1;
  const int lhi = ln >> 4, llo = ln & 15;
  const int m0 = blockIdx.x * 128, n0 = blockIdx.y * 128;

  f32x4 acc[4][4];
  #pragma unroll
  for (int m = 0; m < 4; ++m)
    #pragma unroll
    for (int n = 0; n < 4; ++n) acc[m][n] = 0.0f;

  const int lrow = ln >> 2;           // 0..15 within chunk
  const int lk8  = (ln & 3) * 8;      // element offset along K for the 16B slice

  for (int kt = 0; kt < K; kt += 32){
    #pragma unroll
    for (int cc = 0; cc < 2; ++cc){
      int c = wv * 2 + cc;            // chunk 0..7 (16 rows each)
      gload16(A + (size_t)(m0 + c*16 + lrow) * K + kt + lk8, &sA[c*16][0]);
      gload16(B + (size_t)(n0 + c*16 + lrow) * K + kt + lk8, &sB[c*16][0]);
    }
    __syncthreads();                   // drains vmcnt before barrier (compiler-emitted)

    short8 av[4], bv[4];
    #pragma unroll
    for (int m = 0; m < 4; ++m)
      av[m] = *reinterpret_cast<const short8*>(&sA[wr*64 + m*16 + llo][lhi*8]);
    #pragma unroll
    for (int n = 0; n < 4; ++n)
      bv[n] = *reinterpret_cast<const short8*>(&sB[wc*64 + n*16 + llo][lhi*8]);

    #pragma unroll
    for (int m = 0; m < 4; ++m)
      #pragma unroll
      for (int n = 0; n < 4; ++n)
        mfma16(acc[m][n], av[m], bv[n]);
    __syncthreads();
  }

  // MFMA -> VALU read hazard guard (raw-asm MFMA: compiler doesn't know to pad)
  asm volatile("s_nop 7\n\ts_nop 7\n\ts_nop 7" ::: );

  #pragma unroll
  for (int m = 0; m < 4; ++m){
    #pragma unroll
    for (int j = 0; j < 4; ++j){
      int row = m0 + wr*64 + m*16 + lhi*4 + j;
      #pragma unroll
      for (int n = 0; n < 4; ++n){
        int col = n0 + wc*64 + n*16 + llo;
        float v = acc[m][n][j] + bias[col];
        if (EPI == 1){
          v += add[(size_t)row * N + col];
          Cb[(size_t)row * N + col] = f2bf(v);
        } else {
          Cf[(size_t)row * N + col] = v;
        }
      }
    }
  }
}

// ---------- depthwise 3x3 SAME conv over 32x32 + bias + exact GELU, f32 in -> bf16 out ----------
__global__ void k_dwgelu(const float* __restrict__ t1, const float* __restrict__ dww,
                         const float* __restrict__ dwb, unsigned short* __restrict__ t2)
{
  int idx = blockIdx.x * blockDim.x + threadIdx.x;   // 16384*32
  int hq = idx & 31; int t = idx >> 5;
  int h = hq * 4;
  int n = t & (NT-1); int b = t >> 10;
  int y = n >> 5, x = n & 31;

  float w[4][9];
  #pragma unroll
  for (int i = 0; i < 4; ++i)
    #pragma unroll
    for (int k = 0; k < 9; ++k) w[i][k] = dww[(h+i)*9 + k];

  float a0 = dwb[h+0], a1 = dwb[h+1], a2 = dwb[h+2], a3 = dwb[h+3];
  #pragma unroll
  for (int dy = -1; dy <= 1; ++dy){
    int yy = y + dy; if ((unsigned)yy >= 32u) continue;
    #pragma unroll
    for (int dx = -1; dx <= 1; ++dx){
      int xx = x + dx; if ((unsigned)xx >= 32u) continue;
      float4 v = *reinterpret_cast<const float4*>(&t1[((size_t)b*NT + yy*32 + xx)*HIDN + h]);
      int k = (dy+1)*3 + (dx+1);
      a0 += v.x * w[0][k]; a1 += v.y * w[1][k]; a2 += v.z * w[2][k]; a3 += v.w * w[3][k];
    }
  }
  const float is2 = 0.70710678118654752440f;
  a0 = 0.5f*a0*(1.0f + erff(a0*is2));
  a1 = 0.5f*a1*(1.0f + erff(a1*is2));
  a2 = 0.5f*a2*(1.0f + erff(a2*is2));
  a3 = 0.5f*a3*(1.0f + erff(a3*is2));
  ushort4 o; o.x = f2bf(a0); o.y = f2bf(a1); o.z = f2bf(a2); o.w = f2bf(a3);
  *reinterpret_cast<ushort4*>(&t2[(size_t)t*HIDN + h]) = o;
}

// ---------- raw cosine similarity per token ----------
__global__ void k_csim(const unsigned short* __restrict__ xr, const float* __restrict__ meanb,
                       const float* __restrict__ n1sq, float* __restrict__ csim)
{
  int gw = (blockIdx.x * blockDim.x + threadIdx.x) >> 6;  // 1024 waves
  int ln = threadIdx.x & 63;
  for (int t = gw; t < MTOT; t += 1024){
    int b = t >> 10;
    const unsigned short* xp = xr + (size_t)t*CH;
    const float* mp = meanb + b*CH;
    float d = 0.f, q = 0.f;
    #pragma unroll
    for (int i = 0; i < 12; ++i){
      int c = i*64 + ln;
      float xv = bf2f(xp[c]);
      d += xv * mp[c];
      q += xv * xv;
    }
    for (int off = 32; off; off >>= 1){
      d += __shfl_down(d, off, 64);
      q += __shfl_down(q, off, 64);
    }
    if (ln == 0) csim[t] = d / (sqrtf(n1sq[b]) * sqrtf(q));
  }
}

// ---------- threefry2x32 (JAX), 20 rounds ----------
__device__ __forceinline__ void threefry(unsigned k0, unsigned k1, unsigned x0, unsigned x1,
                                         unsigned& o0, unsigned& o1){
  unsigned ks2 = k0 ^ k1 ^ 0x1BD11BDAu;
  x0 += k0; x1 += k1;
#define TFR(r) { x0 += x1; x1 = (x1 << r) | (x1 >> (32 - r)); x1 ^= x0; }
  TFR(13) TFR(15) TFR(26) TFR(6)  x0 += k1;  x1 += ks2 + 1u;
  TFR(17) TFR(29) TFR(16) TFR(24) x0 += ks2; x1 += k0 + 2u;
  TFR(13) TFR(15) TFR(26) TFR(6)  x0 += k0;  x1 += k1 + 3u;
  TFR(17) TFR(29) TFR(16) TFR(24) x0 += k1;  x1 += ks2 + 4u;
  TFR(13) TFR(15) TFR(26) TFR(6)  x0 += ks2; x1 += k0 + 5u;
#undef TFR
  o0 = x0; o1 = x1;
}

__device__ __forceinline__ float gumbel_from_bits(unsigned bits){
  float f = __uint_as_float((bits >> 9) | 0x3F800000u) - 1.0f;
  const float TINY = 1.17549435e-38f;
  float u = fmaxf(TINY, f + TINY);     // (1-TINY)==1 in fp32
  return -logf(-logf(u));
}

// ---------- per-batch min/max normalize + router MLP + gumbel softmax ----------
__global__ void k_router(const float* __restrict__ csim, const float* __restrict__ r1w,
                         const float* __restrict__ r1b, const float* __restrict__ r2w,
                         const float* __restrict__ r2b, float* __restrict__ out)
{
  int b = blockIdx.x, tid = threadIdx.x;
  __shared__ float cs[NT];
  __shared__ float red[8];
  float lmin = 3.4e38f, lmax = -3.4e38f;
  #pragma unroll
  for (int j = 0; j < 4; ++j){
    float v = csim[b*NT + tid + j*256];
    cs[tid + j*256] = v;
    lmin = fminf(lmin, v); lmax = fmaxf(lmax, v);
  }
  int ln = tid & 63, wv = tid >> 6;
  for (int off = 32; off; off >>= 1){
    lmin = fminf(lmin, __shfl_down(lmin, off, 64));
    lmax = fmaxf(lmax, __shfl_down(lmax, off, 64));
  }
  if (ln == 0){ red[wv] = lmin; red[4+wv] = lmax; }
  __syncthreads();
  float mn = fminf(fminf(red[0], red[1]), fminf(red[2], red[3]));
  float mx = fmaxf(fmaxf(red[4], red[5]), fmaxf(red[6], red[7]));
  float rng = mx - mn;
  bool nz = (rng != 0.0f);

  #pragma unroll
  for (int j = 0; j < 4; ++j){
    int tk = tid + j*256;
    float c0 = cs[tk];
    float v = nz ? (c0 - mn) / rng : c0;
    float l0 = r2b[0], l1 = r2b[1];
    for (int k = 0; k < HIDN; ++k){
      float hh = fmaxf(v * r1w[k] + r1b[k], 0.f);
      l0 += hh * r2w[k];
      l1 += hh * r2w[HIDN + k];
    }
    l0 = 1.f / (1.f + expf(-l0));
    l1 = 1.f / (1.f + expf(-l1));
    int t = b*NT + tk;
    // JAX threefry_partitionable random_bits(32): per element i, counter64 = i,
    // bits = o0 ^ o1 of threefry(key, (hi=0, lo=i))
    unsigned o0, o1;
    threefry(0u, 42u, 0u, (unsigned)(2*t),     o0, o1);
    float g0 = gumbel_from_bits(o0 ^ o1);
    threefry(0u, 42u, 0u, (unsigned)(2*t + 1), o0, o1);
    float g1 = gumbel_from_bits(o0 ^ o1);
    // softmax(l+g)[0] = sigmoid((l0+g0)-(l1+g1))
    out[t] = 1.f / (1.f + expf((l1 + g1) - (l0 + g0)));
  }
}

extern "C" void kernel_launch(void* const* d_in, const int* in_sizes, int n_in,
                              void* d_out, int out_size, void* d_ws, size_t ws_size,
                              hipStream_t stream)
{
  (void)in_sizes; (void)n_in; (void)out_size;
  const float* input  = (const float*)d_in[0];
  const float* input2 = (const float*)d_in[3];
  const float* qkv_w  = (const float*)d_in[4];
  const float* qkv_b  = (const float*)d_in[5];
  const float* fc1_w  = (const float*)d_in[6];
  const float* fc1_b  = (const float*)d_in[7];
  const float* dw_w   = (const float*)d_in[8];
  const float* dw_b   = (const float*)d_in[9];
  const float* fc2_w  = (const float*)d_in[10];
  const float* fc2_b  = (const float*)d_in[11];
  const float* r1_w   = (const float*)d_in[12];
  const float* r1_b   = (const float*)d_in[13];
  const float* r2_w   = (const float*)d_in[14];
  const float* r2_b   = (const float*)d_in[15];

  float* q1 = (float*)d_out;
  float* q2 = q1 + (size_t)MTOT * OUTF;
  float* router = q1 + (size_t)2 * MTOT * OUTF;

  if (ws_size < 67000000u) return;   // refuse to run with insufficient scratch

  char* ws = (char*)d_ws;
  unsigned short* x1b = (unsigned short*)ws; ws += (size_t)MTOT*CH*2;   // input bf16
  unsigned short* xrb = (unsigned short*)ws; ws += (size_t)MTOT*CH*2;   // input2 bf16 -> refine bf16
  unsigned short* wqb = (unsigned short*)ws; ws += (size_t)OUTF*CH*2;   // qkv_w bf16
  unsigned short* w1b = (unsigned short*)ws; ws += (size_t)HIDN*CH*2;   // fc1_w bf16
  unsigned short* w2b = (unsigned short*)ws; ws += (size_t)CH*HIDN*2;   // fc2_w bf16
  float*          t1  = (float*)ws;          ws += (size_t)MTOT*HIDN*4; // fc1 out f32
  unsigned short* t2  = (unsigned short*)ws; ws += (size_t)MTOT*HIDN*2; // conv+gelu out bf16
  float*          mb  = (float*)ws;          ws += (size_t)BQ*CH*4;     // per-batch mean
  float*          n1sq= (float*)ws;          ws += 256;                 // ||mean||^2 per batch
  float*          csim= (float*)ws;          ws += (size_t)MTOT*4;      // raw cosine sim

  auto cvt = [&](const float* s, unsigned short* d, int n){
    k_f2bf<<<dim3((n/4 + 255)/256), 256, 0, stream>>>(s, d, n);
  };
  cvt(input,  x1b, MTOT*CH);
  cvt(input2, xrb, MTOT*CH);
  cvt(qkv_w,  wqb, OUTF*CH);
  cvt(fc1_w,  w1b, HIDN*CH);
  cvt(fc2_w,  w2b, CH*HIDN);

  hipMemsetAsync(n1sq, 0, 64, stream);
  k_mean<<<dim3(BQ, 6), 256, 0, stream>>>(input, mb, n1sq);

  // fc1: [16384,768] x [128,768]^T -> t1 f32
  k_gemm<0><<<dim3(MTOT/128, HIDN/128), 256, 0, stream>>>(
      xrb, w1b, fc1_b, nullptr, t1, nullptr, MTOT, HIDN, CH);
  // depthwise conv + gelu -> t2 bf16
  k_dwgelu<<<dim3(MTOT*32/256), 256, 0, stream>>>(t1, dw_w, dw_b, t2);
  // fc2 + input2 add -> refine bf16 (overwrites xrb; input2-bf16 no longer needed)
  k_gemm<1><<<dim3(MTOT/128, CH/128), 256, 0, stream>>>(
      t2, w2b, fc2_b, input2, nullptr, xrb, MTOT, CH, HIDN);
  // q1 = input @ qkv_w^T + b
  k_gemm<0><<<dim3(MTOT/128, OUTF/128), 256, 0, stream>>>(
      x1b, wqb, qkv_b, nullptr, q1, nullptr, MTOT, OUTF, CH);
  // q2 = refine @ qkv_w^T + b
  k_gemm<0><<<dim3(MTOT/128, OUTF/128), 256, 0, stream>>>(
      xrb, wqb, qkv_b, nullptr, q2, nullptr, MTOT, OUTF, CH);

  k_csim<<<dim3(256), 256, 0, stream>>>(xrb, mb, n1sq, csim);
  k_router<<<dim3(BQ), 256, 0, stream>>>(csim, r1_w, r1_b, r2_w, r2_b, router);
}

// Round 2
// 312.818 us; speedup vs baseline: 1.0934x; 1.0934x over previous
//
#include <hip/hip_runtime.h>
#include <cstdint>
#include <cstddef>

#define BQ 16
#define NT 1024
#define CH 768
#define HIDN 128
#define OUTF 2304
#define MTOT (BQ*NT)   // 16384 tokens

typedef __attribute__((ext_vector_type(4))) float f32x4;
typedef __attribute__((ext_vector_type(8))) short short8;   // 8 x bf16 payload

// ---------- small helpers ----------
__device__ __forceinline__ unsigned short f2bf(float f){
  unsigned u = __float_as_uint(f);
  u += 0x7FFFu + ((u >> 16) & 1u);      // RNE
  return (unsigned short)(u >> 16);
}
__device__ __forceinline__ float bf2f(unsigned short h){
  return __uint_as_float(((unsigned)h) << 16);
}

__device__ __forceinline__ void gload16(const void* g, void* l){
  // async global->LDS, 16B per lane; LDS dest is wave-uniform base + lane*16
  __builtin_amdgcn_global_load_lds((const __attribute__((address_space(1))) void*)g,
                                   (__attribute__((address_space(3))) void*)l, 16, 0, 0);
}

__device__ __forceinline__ void mfma16(f32x4& d, short8 a, short8 b){
  asm volatile("v_mfma_f32_16x16x32_bf16 %0, %1, %2, %0" : "+v"(d) : "v"(a), "v"(b));
}

// ---------- fp32 -> bf16 convert ----------
__global__ void k_f2bf(const float* __restrict__ src, unsigned short* __restrict__ dst, int n){
  int i = (blockIdx.x * blockDim.x + threadIdx.x) * 4;
  if (i + 3 >= n) { for (int j = i; j < n; ++j) dst[j] = f2bf(src[j]); return; }
  float4 v = *reinterpret_cast<const float4*>(src + i);
  ushort4 o;
  o.x = f2bf(v.x); o.y = f2bf(v.y); o.z = f2bf(v.z); o.w = f2bf(v.w);
  *reinterpret_cast<ushort4*>(dst + i) = o;
}

// ---------- per-batch token mean of `input` + ||mean||^2 ----------
__global__ void k_mean(const float* __restrict__ input, float* __restrict__ meanb,
                       float* __restrict__ n1sq){
  int b = blockIdx.x, cg = blockIdx.y;
  int tid = threadIdx.x;
  int h = tid >> 7, cl = tid & 127;
  int c = cg * 128 + cl;
  const float* ip = input + (size_t)b*NT*CH + (size_t)h*512*CH + c;
  float s = 0.f;
  #pragma unroll 4
  for (int n = 0; n < 512; ++n) s += ip[(size_t)n*CH];
  __shared__ float tmp[256];
  tmp[tid] = s; __syncthreads();
  if (tid < 128){
    float m = (tmp[tid] + tmp[tid+128]) * (1.0f/1024.0f);
    meanb[b*CH + cg*128 + tid] = m;
    float q = m * m;
    for (int off = 32; off; off >>= 1) q += __shfl_down(q, off, 64);
    if ((tid & 63) == 0) atomicAdd(&n1sq[b], q);
  }
}

// ---------- m97-structure MFMA GEMM (kept for fc1/fc2 small shapes) ----------
template<int EPI>
__global__ __launch_bounds__(256, 2)
void k_gemm(const unsigned short* __restrict__ A, const unsigned short* __restrict__ B,
            const float* __restrict__ bias, const float* __restrict__ add,
            float* __restrict__ Cf, unsigned short* __restrict__ Cb,
            int M, int N, int K)
{
  __shared__ unsigned short sA[128][32];
  __shared__ unsigned short sB[128][32];
  const int tid = threadIdx.x;
  const int wv = tid >> 6, ln = tid & 63;
  const int wr = wv >> 1, wc = wv & 1;
  const int lhi = ln >> 4, llo = ln & 15;
  const int m0 = blockIdx.x * 128, n0 = blockIdx.y * 128;

  f32x4 acc[4][4];
  #pragma unroll
  for (int m = 0; m < 4; ++m)
    #pragma unroll
    for (int n = 0; n < 4; ++n) acc[m][n] = 0.0f;

  const int lrow = ln >> 2;
  const int lk8  = (ln & 3) * 8;

  for (int kt = 0; kt < K; kt += 32){
    #pragma unroll
    for (int cc = 0; cc < 2; ++cc){
      int c = wv * 2 + cc;
      gload16(A + (size_t)(m0 + c*16 + lrow) * K + kt + lk8, &sA[c*16][0]);
      gload16(B + (size_t)(n0 + c*16 + lrow) * K + kt + lk8, &sB[c*16][0]);
    }
    __syncthreads();

    short8 av[4], bv[4];
    #pragma unroll
    for (int m = 0; m < 4; ++m)
      av[m] = *reinterpret_cast<const short8*>(&sA[wr*64 + m*16 + llo][lhi*8]);
    #pragma unroll
    for (int n = 0; n < 4; ++n)
      bv[n] = *reinterpret_cast<const short8*>(&sB[wc*64 + n*16 + llo][lhi*8]);

    #pragma unroll
    for (int m = 0; m < 4; ++m)
      #pragma unroll
      for (int n = 0; n < 4; ++n)
        mfma16(acc[m][n], av[m], bv[n]);
    __syncthreads();
  }

  asm volatile("s_nop 7\n\ts_nop 7\n\ts_nop 7" ::: );

  #pragma unroll
  for (int m = 0; m < 4; ++m){
    #pragma unroll
    for (int j = 0; j < 4; ++j){
      int row = m0 + wr*64 + m*16 + lhi*4 + j;
      #pragma unroll
      for (int n = 0; n < 4; ++n){
        int col = n0 + wc*64 + n*16 + llo;
        float v = acc[m][n][j] + bias[col];
        if (EPI == 1){
          v += add[(size_t)row * N + col];
          Cb[(size_t)row * N + col] = f2bf(v);
        } else {
          Cf[(size_t)row * N + col] = v;
        }
      }
    }
  }
}

// ============================================================================
// 256x256 8-phase GEMM (T1+T2+T3+T4+T5), C[M,N] = A[M,K] * B[N,K]^T + bias
// 512 threads = 8 waves (2M x 4N). BK=64, LDS 128 KiB double-buffered.
// LDS layout: [mat(A=0,B=1)][buf][half(128 rows)][row 128B, 8 x 16B slots]
// T2 swizzle: stored slot = logical slot ^ (row&7) — applied on the GLOBAL
// source for global_load_lds (linear LDS dest) and on the ds_read address.
// Staging order per tile t (1 half per phase): ph1 A1(t+1), ph2 B0(t+1),
// ph3 A0(t+2), ph4 B1(t+2); boundary s_waitcnt vmcnt(4) (= the 2 newest
// halves stay in flight). Quadrant order: A0B0, A0B1, A1B1, A1B0 so each
// half's last LDS read is >=1 barrier before its region is restaged.
// ============================================================================
#define STAGE(matB_, buf_, h_, t_) { \
    const unsigned short* g_ = ((matB_) ? Bbase : Abase) + (size_t)(h_)*128*K + (size_t)(t_)*64; \
    char* d_ = ldsWaveDst + (matB_)*65536 + (buf_)*32768 + (h_)*16384; \
    gload16(g_, d_); \
    gload16(g_ + rowK64, d_ + 8192); \
  }

#define PH_OPEN() \
    asm volatile("s_barrier" ::: "memory"); \
    asm volatile("s_waitcnt lgkmcnt(0)" ::: "memory"); \
    __builtin_amdgcn_sched_barrier(0); \
    __builtin_amdgcn_s_setprio(1);

#define PH_CLOSE() \
    __builtin_amdgcn_s_setprio(0); \
    asm volatile("s_barrier" ::: "memory");

#define MF16(mb, nb, BV) \
    _Pragma("unroll") \
    for (int ks = 0; ks < 2; ++ks) \
      _Pragma("unroll") \
      for (int mf = 0; mf < 4; ++mf) \
        _Pragma("unroll") \
        for (int nf = 0; nf < 2; ++nf) \
          mfma16(acc[(mb)+mf][(nb)+nf], av[mf][ks], BV[nf][ks]);

#define TILE(t_, b_) { \
    const int t = (t_); const int b = (b_); \
    _Pragma("unroll") for (int mf = 0; mf < 4; ++mf){ av[mf][0]=ldA(b,mf,0); av[mf][1]=ldA(b,mf,1); } \
    _Pragma("unroll") for (int nf = 0; nf < 2; ++nf){ b0v[nf][0]=ldB(b,nf,0); b0v[nf][1]=ldB(b,nf,1); } \
    if (t+1 < T) STAGE(0, b^1, 1, t+1); \
    PH_OPEN(); MF16(0,0,b0v); PH_CLOSE(); \
    _Pragma("unroll") for (int nf = 0; nf < 2; ++nf){ b1v[nf][0]=ldB(b,2+nf,0); b1v[nf][1]=ldB(b,2+nf,1); } \
    if (t+1 < T) STAGE(1, b^1, 0, t+1); \
    PH_OPEN(); MF16(0,2,b1v); PH_CLOSE(); \
    _Pragma("unroll") for (int mf = 0; mf < 4; ++mf){ av[mf][0]=ldA(b,4+mf,0); av[mf][1]=ldA(b,4+mf,1); } \
    if (t+2 < T) STAGE(0, b, 0, t+2); \
    PH_OPEN(); MF16(4,2,b1v); PH_CLOSE(); \
    if (t+2 < T) STAGE(1, b, 1, t+2); \
    PH_OPEN(); MF16(4,0,b0v); \
    __builtin_amdgcn_s_setprio(0); \
    if (t+2 < T) { asm volatile("s_waitcnt vmcnt(4)" ::: "memory"); } \
    else         { asm volatile("s_waitcnt vmcnt(0)" ::: "memory"); } \
    asm volatile("s_barrier" ::: "memory"); \
  }

template<int T>   // K = T*64, T even
__global__ __launch_bounds__(512, 2)
void k_gemm256(const unsigned short* __restrict__ A,
               const unsigned short* __restrict__ B,
               const float* __restrict__ bias,
               float* __restrict__ C,
               int N, int K, int nbn)
{
  __shared__ __align__(1024) char lds8[131072];
  const int tid = threadIdx.x;
  const int ln = tid & 63, wv = tid >> 6;
  const int wm = wv >> 2, wn = wv & 3;
  const int llo = ln & 15, lhi = ln >> 4;

  // T1: XCD-aware block swizzle (grid % 8 == 0 guaranteed by caller)
  const int nwg = gridDim.x;
  const int cpx = nwg >> 3;
  const int bid = blockIdx.x;
  const int swz = (bid & 7) * cpx + (bid >> 3);
  const int bm = swz / nbn, bn = swz % nbn;
  const int m0 = bm * 256, n0 = bn * 256;

  // ---- staging (pre-swizzled global source, linear LDS dest) ----
  const int srow = tid >> 3;                    // 0..63
  const int sslot = (tid & 7) ^ (srow & 7);     // inverse swizzle on source
  const unsigned short* Abase = A + (size_t)(m0 + srow) * K + sslot * 8;
  const unsigned short* Bbase = B + (size_t)(n0 + srow) * K + sslot * 8;
  const size_t rowK64 = (size_t)64 * K;
  char* ldsWaveDst = lds8 + (wv << 10);

  // ---- ds_read bases (swizzled) ----
  const int swz0 = ((lhi ^ (ln & 7)) << 4);
  const char* aRd0 = lds8 + (wm*64 + llo)*128 + swz0;
  const char* aRd1 = lds8 + (wm*64 + llo)*128 + (swz0 ^ 64);
  const char* bRd0 = lds8 + 65536 + (wn*32 + llo)*128 + swz0;
  const char* bRd1 = lds8 + 65536 + (wn*32 + llo)*128 + (swz0 ^ 64);

  auto ldA = [&](int b, int mf, int ks) -> short8 {
    const char* p = (ks ? aRd1 : aRd0) + b*32768 + (mf>>2)*16384 + (mf&3)*2048;
    return *reinterpret_cast<const short8*>(p);
  };
  auto ldB = [&](int b, int nf, int ks) -> short8 {
    const char* p = (ks ? bRd1 : bRd0) + b*32768 + (nf>>1)*16384 + (nf&1)*2048;
    return *reinterpret_cast<const short8*>(p);
  };

  f32x4 acc[8][4];
  #pragma unroll
  for (int m = 0; m < 8; ++m)
    #pragma unroll
    for (int n = 0; n < 4; ++n) acc[m][n] = 0.0f;

  // ---- prologue: tile0 all 4 halves, then A0(1), B1(1) ----
  STAGE(0, 0, 0, 0);   // A0(0)
  STAGE(1, 0, 1, 0);   // B1(0)
  STAGE(0, 0, 1, 0);   // A1(0)
  STAGE(1, 0, 0, 0);   // B0(0)
  STAGE(0, 1, 0, 1);   // A0(1)
  STAGE(1, 1, 1, 1);   // B1(1)
  asm volatile("s_waitcnt vmcnt(4)" ::: "memory");
  asm volatile("s_barrier" ::: "memory");

  short8 av[4][2], b0v[2][2], b1v[2][2];
  #pragma unroll 1
  for (int t0 = 0; t0 < T; t0 += 2){
    TILE(t0,   0);
    TILE(t0+1, 1);
  }

  // MFMA -> VALU hazard guard
  asm volatile("s_nop 7\n\ts_nop 7\n\ts_nop 7" ::: );

  #pragma unroll
  for (int mf = 0; mf < 8; ++mf){
    const int row = m0 + (mf>>2)*128 + wm*64 + (mf&3)*16 + lhi*4;
    #pragma unroll
    for (int j = 0; j < 4; ++j){
      #pragma unroll
      for (int nf = 0; nf < 4; ++nf){
        const int col = n0 + (nf>>1)*128 + wn*32 + (nf&1)*16 + llo;
        C[(size_t)(row + j) * N + col] = acc[mf][nf][j] + bias[col];
      }
    }
  }
}

// ---------- depthwise 3x3 SAME conv over 32x32 + bias + exact GELU ----------
__global__ void k_dwgelu(const float* __restrict__ t1, const float* __restrict__ dww,
                         const float* __restrict__ dwb, unsigned short* __restrict__ t2)
{
  int idx = blockIdx.x * blockDim.x + threadIdx.x;
  int hq = idx & 31; int t = idx >> 5;
  int h = hq * 4;
  int n = t & (NT-1); int b = t >> 10;
  int y = n >> 5, x = n & 31;

  float w[4][9];
  #pragma unroll
  for (int i = 0; i < 4; ++i)
    #pragma unroll
    for (int k = 0; k < 9; ++k) w[i][k] = dww[(h+i)*9 + k];

  float a0 = dwb[h+0], a1 = dwb[h+1], a2 = dwb[h+2], a3 = dwb[h+3];
  #pragma unroll
  for (int dy = -1; dy <= 1; ++dy){
    int yy = y + dy; if ((unsigned)yy >= 32u) continue;
    #pragma unroll
    for (int dx = -1; dx <= 1; ++dx){
      int xx = x + dx; if ((unsigned)xx >= 32u) continue;
      float4 v = *reinterpret_cast<const float4*>(&t1[((size_t)b*NT + yy*32 + xx)*HIDN + h]);
      int k = (dy+1)*3 + (dx+1);
      a0 += v.x * w[0][k]; a1 += v.y * w[1][k]; a2 += v.z * w[2][k]; a3 += v.w * w[3][k];
    }
  }
  const float is2 = 0.70710678118654752440f;
  a0 = 0.5f*a0*(1.0f + erff(a0*is2));
  a1 = 0.5f*a1*(1.0f + erff(a1*is2));
  a2 = 0.5f*a2*(1.0f + erff(a2*is2));
  a3 = 0.5f*a3*(1.0f + erff(a3*is2));
  ushort4 o; o.x = f2bf(a0); o.y = f2bf(a1); o.z = f2bf(a2); o.w = f2bf(a3);
  *reinterpret_cast<ushort4*>(&t2[(size_t)t*HIDN + h]) = o;
}

// ---------- raw cosine similarity per token ----------
__global__ void k_csim(const unsigned short* __restrict__ xr, const float* __restrict__ meanb,
                       const float* __restrict__ n1sq, float* __restrict__ csim)
{
  int gw = (blockIdx.x * blockDim.x + threadIdx.x) >> 6;
  int ln = threadIdx.x & 63;
  for (int t = gw; t < MTOT; t += 1024){
    int b = t >> 10;
    const unsigned short* xp = xr + (size_t)t*CH;
    const float* mp = meanb + b*CH;
    float d = 0.f, q = 0.f;
    #pragma unroll
    for (int i = 0; i < 12; ++i){
      int c = i*64 + ln;
      float xv = bf2f(xp[c]);
      d += xv * mp[c];
      q += xv * xv;
    }
    for (int off = 32; off; off >>= 1){
      d += __shfl_down(d, off, 64);
      q += __shfl_down(q, off, 64);
    }
    if (ln == 0) csim[t] = d / (sqrtf(n1sq[b]) * sqrtf(q));
  }
}

// ---------- threefry2x32 (JAX), 20 rounds ----------
__device__ __forceinline__ void threefry(unsigned k0, unsigned k1, unsigned x0, unsigned x1,
                                         unsigned& o0, unsigned& o1){
  unsigned ks2 = k0 ^ k1 ^ 0x1BD11BDAu;
  x0 += k0; x1 += k1;
#define TFR(r) { x0 += x1; x1 = (x1 << r) | (x1 >> (32 - r)); x1 ^= x0; }
  TFR(13) TFR(15) TFR(26) TFR(6)  x0 += k1;  x1 += ks2 + 1u;
  TFR(17) TFR(29) TFR(16) TFR(24) x0 += ks2; x1 += k0 + 2u;
  TFR(13) TFR(15) TFR(26) TFR(6)  x0 += k0;  x1 += k1 + 3u;
  TFR(17) TFR(29) TFR(16) TFR(24) x0 += k1;  x1 += ks2 + 4u;
  TFR(13) TFR(15) TFR(26) TFR(6)  x0 += ks2; x1 += k0 + 5u;
#undef TFR
  o0 = x0; o1 = x1;
}

__device__ __forceinline__ float gumbel_from_bits(unsigned bits){
  float f = __uint_as_float((bits >> 9) | 0x3F800000u) - 1.0f;
  const float TINY = 1.17549435e-38f;
  float u = fmaxf(TINY, f + TINY);
  return -logf(-logf(u));
}

// ---------- per-batch min/max normalize + router MLP + gumbel softmax ----------
__global__ void k_router(const float* __restrict__ csim, const float* __restrict__ r1w,
                         const float* __restrict__ r1b, const float* __restrict__ r2w,
                         const float* __restrict__ r2b, float* __restrict__ out)
{
  int b = blockIdx.x, tid = threadIdx.x;
  __shared__ float cs[NT];
  __shared__ float red[8];
  float lmin = 3.4e38f, lmax = -3.4e38f;
  #pragma unroll
  for (int j = 0; j < 4; ++j){
    float v = csim[b*NT + tid + j*256];
    cs[tid + j*256] = v;
    lmin = fminf(lmin, v); lmax = fmaxf(lmax, v);
  }
  int ln = tid & 63, wv = tid >> 6;
  for (int off = 32; off; off >>= 1){
    lmin = fminf(lmin, __shfl_down(lmin, off, 64));
    lmax = fmaxf(lmax, __shfl_down(lmax, off, 64));
  }
  if (ln == 0){ red[wv] = lmin; red[4+wv] = lmax; }
  __syncthreads();
  float mn = fminf(fminf(red[0], red[1]), fminf(red[2], red[3]));
  float mx = fmaxf(fmaxf(red[4], red[5]), fmaxf(red[6], red[7]));
  float rng = mx - mn;
  bool nz = (rng != 0.0f);

  #pragma unroll
  for (int j = 0; j < 4; ++j){
    int tk = tid + j*256;
    float c0 = cs[tk];
    float v = nz ? (c0 - mn) / rng : c0;
    float l0 = r2b[0], l1 = r2b[1];
    for (int k = 0; k < HIDN; ++k){
      float hh = fmaxf(v * r1w[k] + r1b[k], 0.f);
      l0 += hh * r2w[k];
      l1 += hh * r2w[HIDN + k];
    }
    l0 = 1.f / (1.f + expf(-l0));
    l1 = 1.f / (1.f + expf(-l1));
    int t = b*NT + tk;
    unsigned o0, o1;
    threefry(0u, 42u, 0u, (unsigned)(2*t),     o0, o1);
    float g0 = gumbel_from_bits(o0 ^ o1);
    threefry(0u, 42u, 0u, (unsigned)(2*t + 1), o0, o1);
    float g1 = gumbel_from_bits(o0 ^ o1);
    out[t] = 1.f / (1.f + expf((l1 + g1) - (l0 + g0)));
  }
}

extern "C" void kernel_launch(void* const* d_in, const int* in_sizes, int n_in,
                              void* d_out, int out_size, void* d_ws, size_t ws_size,
                              hipStream_t stream)
{
  (void)in_sizes; (void)n_in; (void)out_size;
  const float* input  = (const float*)d_in[0];
  const float* input2 = (const float*)d_in[3];
  const float* qkv_w  = (const float*)d_in[4];
  const float* qkv_b  = (const float*)d_in[5];
  const float* fc1_w  = (const float*)d_in[6];
  const float* fc1_b  = (const float*)d_in[7];
  const float* dw_w   = (const float*)d_in[8];
  const float* dw_b   = (const float*)d_in[9];
  const float* fc2_w  = (const float*)d_in[10];
  const float* fc2_b  = (const float*)d_in[11];
  const float* r1_w   = (const float*)d_in[12];
  const float* r1_b   = (const float*)d_in[13];
  const float* r2_w   = (const float*)d_in[14];
  const float* r2_b   = (const float*)d_in[15];

  float* q1 = (float*)d_out;
  float* router = q1 + (size_t)2 * MTOT * OUTF;

  if (ws_size < 67000000u) return;

  char* ws = (char*)d_ws;
  unsigned short* x1b = (unsigned short*)ws; ws += (size_t)MTOT*CH*2;   // input bf16   } contiguous:
  unsigned short* xrb = (unsigned short*)ws; ws += (size_t)MTOT*CH*2;   // refine bf16  } A=[x1b;xrb]
  unsigned short* wqb = (unsigned short*)ws; ws += (size_t)OUTF*CH*2;
  unsigned short* w1b = (unsigned short*)ws; ws += (size_t)HIDN*CH*2;
  unsigned short* w2b = (unsigned short*)ws; ws += (size_t)CH*HIDN*2;
  float*          t1  = (float*)ws;          ws += (size_t)MTOT*HIDN*4;
  unsigned short* t2  = (unsigned short*)ws; ws += (size_t)MTOT*HIDN*2;
  float*          mb  = (float*)ws;          ws += (size_t)BQ*CH*4;
  float*          n1sq= (float*)ws;          ws += 256;
  float*          csim= (float*)ws;          ws += (size_t)MTOT*4;

  auto cvt = [&](const float* s, unsigned short* d, int n){
    k_f2bf<<<dim3((n/4 + 255)/256), 256, 0, stream>>>(s, d, n);
  };
  cvt(input,  x1b, MTOT*CH);
  cvt(input2, xrb, MTOT*CH);
  cvt(qkv_w,  wqb, OUTF*CH);
  cvt(fc1_w,  w1b, HIDN*CH);
  cvt(fc2_w,  w2b, CH*HIDN);

  hipMemsetAsync(n1sq, 0, 64, stream);
  k_mean<<<dim3(BQ, 6), 256, 0, stream>>>(input, mb, n1sq);

  // fc1: [16384,768] x [128,768]^T -> t1 f32
  k_gemm<0><<<dim3(MTOT/128, HIDN/128), 256, 0, stream>>>(
      xrb, w1b, fc1_b, nullptr, t1, nullptr, MTOT, HIDN, CH);
  // depthwise conv + gelu -> t2 bf16
  k_dwgelu<<<dim3(MTOT*32/256), 256, 0, stream>>>(t1, dw_w, dw_b, t2);
  // fc2 + input2 add -> refine bf16 (into xrb, completing A=[input;refine])
  k_gemm<1><<<dim3(MTOT/128, CH/128), 256, 0, stream>>>(
      t2, w2b, fc2_b, input2, nullptr, xrb, MTOT, CH, HIDN);

  // combined qkv: [q1;q2] = [input;refine] @ qkv_w^T + b  (M = 32768)
  // grid = (32768/256) * (2304/256) = 128*9 = 1152 blocks (divisible by 8)
  k_gemm256<CH/64><<<dim3((2*MTOT/256) * (OUTF/256)), 512, 0, stream>>>(
      x1b, wqb, qkv_b, q1, OUTF, CH, OUTF/256);

  k_csim<<<dim3(256), 256, 0, stream>>>(xrb, mb, n1sq, csim);
  k_router<<<dim3(BQ), 256, 0, stream>>>(csim, r1_w, r1_b, r2_w, r2_b, router);
}

// Round 3
// 287.122 us; speedup vs baseline: 1.1912x; 1.0895x over previous
//
#include <hip/hip_runtime.h>
#include <cstdint>
#include <cstddef>

#define BQ 16
#define NT 1024
#define CH 768
#define HIDN 128
#define OUTF 2304
#define MTOT (BQ*NT)   // 16384 tokens

typedef __attribute__((ext_vector_type(4))) float f32x4;
typedef __attribute__((ext_vector_type(8))) short short8;   // 8 x bf16 payload

// ---------- small helpers ----------
__device__ __forceinline__ unsigned short f2bf(float f){
  unsigned u = __float_as_uint(f);
  u += 0x7FFFu + ((u >> 16) & 1u);      // RNE
  return (unsigned short)(u >> 16);
}
__device__ __forceinline__ float bf2f(unsigned short h){
  return __uint_as_float(((unsigned)h) << 16);
}

__device__ __forceinline__ void gload16(const void* g, void* l){
  __builtin_amdgcn_global_load_lds((const __attribute__((address_space(1))) void*)g,
                                   (__attribute__((address_space(3))) void*)l, 16, 0, 0);
}

__device__ __forceinline__ void mfma16(f32x4& d, short8 a, short8 b){
  asm volatile("v_mfma_f32_16x16x32_bf16 %0, %1, %2, %0" : "+v"(d) : "v"(a), "v"(b));
}

// ---------- fused fp32 -> bf16 convert of all 5 tensors ----------
// segments: input (12582912), input2 (12582912), qkv_w (1769472),
// fc1_w (98304), fc2_w (98304); all divisible by 4; total/4/256 = 26496 blocks
__global__ void k_f2bf_all(const float* __restrict__ in0, const float* __restrict__ in1,
                           const float* __restrict__ in2, const float* __restrict__ in3,
                           const float* __restrict__ in4,
                           unsigned short* __restrict__ o0, unsigned short* __restrict__ o1,
                           unsigned short* __restrict__ o2, unsigned short* __restrict__ o3,
                           unsigned short* __restrict__ o4)
{
  long i = (long)(blockIdx.x * 256 + threadIdx.x) * 4;
  const float* s; unsigned short* d; long off;
  if      (i < 12582912L){ s = in0; d = o0; off = i; }
  else if (i < 25165824L){ s = in1; d = o1; off = i - 12582912L; }
  else if (i < 26935296L){ s = in2; d = o2; off = i - 25165824L; }
  else if (i < 27033600L){ s = in3; d = o3; off = i - 26935296L; }
  else                   { s = in4; d = o4; off = i - 27033600L; }
  float4 v = *reinterpret_cast<const float4*>(s + off);
  ushort4 o;
  o.x = f2bf(v.x); o.y = f2bf(v.y); o.z = f2bf(v.z); o.w = f2bf(v.w);
  *reinterpret_cast<ushort4*>(d + off) = o;
}

// ---------- per-batch token mean of `input` + ||mean||^2 ----------
__global__ void k_mean(const float* __restrict__ input, float* __restrict__ meanb,
                       float* __restrict__ n1sq){
  int b = blockIdx.x, cg = blockIdx.y;
  int tid = threadIdx.x;
  int h = tid >> 7, cl = tid & 127;
  int c = cg * 128 + cl;
  const float* ip = input + (size_t)b*NT*CH + (size_t)h*512*CH + c;
  float s = 0.f;
  #pragma unroll 4
  for (int n = 0; n < 512; ++n) s += ip[(size_t)n*CH];
  __shared__ float tmp[256];
  tmp[tid] = s; __syncthreads();
  if (tid < 128){
    float m = (tmp[tid] + tmp[tid+128]) * (1.0f/1024.0f);
    meanb[b*CH + cg*128 + tid] = m;
    float q = m * m;
    for (int off = 32; off; off >>= 1) q += __shfl_down(q, off, 64);
    if ((tid & 63) == 0) atomicAdd(&n1sq[b], q);
  }
}

// ---------- m97-structure MFMA GEMM (fc1 / fc2 shapes) ----------
// EPI 0: Cf = acc + bias (f32). EPI 1: Cb = bf16(acc + bias + bf2f(addb)),
//        plus per-row csim partials (dot with meanb, normsq) into part.
template<int EPI>
__global__ __launch_bounds__(256, 2)
void k_gemm(const unsigned short* __restrict__ A, const unsigned short* __restrict__ B,
            const float* __restrict__ bias, const unsigned short* __restrict__ addb,
            float* __restrict__ Cf, unsigned short* __restrict__ Cb,
            const float* __restrict__ meanb, float* __restrict__ part,
            int M, int N, int K)
{
  __shared__ unsigned short sA[128][32];
  __shared__ unsigned short sB[128][32];
  const int tid = threadIdx.x;
  const int wv = tid >> 6, ln = tid & 63;
  const int wr = wv >> 1, wc = wv & 1;
  const int lhi = ln >> 4, llo = ln & 15;
  const int m0 = blockIdx.x * 128, n0 = blockIdx.y * 128;

  f32x4 acc[4][4];
  #pragma unroll
  for (int m = 0; m < 4; ++m)
    #pragma unroll
    for (int n = 0; n < 4; ++n) acc[m][n] = 0.0f;

  const int lrow = ln >> 2;
  const int lk8  = (ln & 3) * 8;

  for (int kt = 0; kt < K; kt += 32){
    #pragma unroll
    for (int cc = 0; cc < 2; ++cc){
      int c = wv * 2 + cc;
      gload16(A + (size_t)(m0 + c*16 + lrow) * K + kt + lk8, &sA[c*16][0]);
      gload16(B + (size_t)(n0 + c*16 + lrow) * K + kt + lk8, &sB[c*16][0]);
    }
    __syncthreads();

    short8 av[4], bv[4];
    #pragma unroll
    for (int m = 0; m < 4; ++m)
      av[m] = *reinterpret_cast<const short8*>(&sA[wr*64 + m*16 + llo][lhi*8]);
    #pragma unroll
    for (int n = 0; n < 4; ++n)
      bv[n] = *reinterpret_cast<const short8*>(&sB[wc*64 + n*16 + llo][lhi*8]);

    #pragma unroll
    for (int m = 0; m < 4; ++m)
      #pragma unroll
      for (int n = 0; n < 4; ++n)
        mfma16(acc[m][n], av[m], bv[n]);
    __syncthreads();
  }

  asm volatile("s_nop 7\n\ts_nop 7\n\ts_nop 7" ::: );

  if (EPI == 0){
    #pragma unroll
    for (int m = 0; m < 4; ++m){
      #pragma unroll
      for (int j = 0; j < 4; ++j){
        int row = m0 + wr*64 + m*16 + lhi*4 + j;
        #pragma unroll
        for (int n = 0; n < 4; ++n){
          int col = n0 + wc*64 + n*16 + llo;
          Cf[(size_t)row * N + col] = acc[m][n][j] + bias[col];
        }
      }
    }
  } else {
    const int bb = m0 >> 10;                       // batch (block fully inside one)
    const float* mp = meanb + bb * CH;
    #pragma unroll
    for (int m = 0; m < 4; ++m){
      #pragma unroll
      for (int j = 0; j < 4; ++j){
        int row = m0 + wr*64 + m*16 + lhi*4 + j;
        float dsum = 0.f, qsum = 0.f;
        #pragma unroll
        for (int n = 0; n < 4; ++n){
          int col = n0 + wc*64 + n*16 + llo;
          float v = acc[m][n][j] + bias[col] + bf2f(addb[(size_t)row * N + col]);
          Cb[(size_t)row * N + col] = f2bf(v);
          dsum += v * mp[col];
          qsum += v * v;
        }
        #pragma unroll
        for (int off = 1; off < 16; off <<= 1){
          dsum += __shfl_xor(dsum, off, 64);
          qsum += __shfl_xor(qsum, off, 64);
        }
        if (llo == 0){
          size_t pi = (size_t)row * 24 + blockIdx.y * 4 + wc * 2;
          part[pi] = dsum; part[pi + 1] = qsum;
        }
      }
    }
  }
}

// ============================================================================
// 256x256 8-phase GEMM (T1+T2+T3+T4+T5) — unchanged from round 2 (validated)
// ============================================================================
#define STAGE(matB_, buf_, h_, t_) { \
    const unsigned short* g_ = ((matB_) ? Bbase : Abase) + (size_t)(h_)*128*K + (size_t)(t_)*64; \
    char* d_ = ldsWaveDst + (matB_)*65536 + (buf_)*32768 + (h_)*16384; \
    gload16(g_, d_); \
    gload16(g_ + rowK64, d_ + 8192); \
  }

#define PH_OPEN() \
    asm volatile("s_barrier" ::: "memory"); \
    asm volatile("s_waitcnt lgkmcnt(0)" ::: "memory"); \
    __builtin_amdgcn_sched_barrier(0); \
    __builtin_amdgcn_s_setprio(1);

#define PH_CLOSE() \
    __builtin_amdgcn_s_setprio(0); \
    asm volatile("s_barrier" ::: "memory");

#define MF16(mb, nb, BV) \
    _Pragma("unroll") \
    for (int ks = 0; ks < 2; ++ks) \
      _Pragma("unroll") \
      for (int mf = 0; mf < 4; ++mf) \
        _Pragma("unroll") \
        for (int nf = 0; nf < 2; ++nf) \
          mfma16(acc[(mb)+mf][(nb)+nf], av[mf][ks], BV[nf][ks]);

#define TILE(t_, b_) { \
    const int t = (t_); const int b = (b_); \
    _Pragma("unroll") for (int mf = 0; mf < 4; ++mf){ av[mf][0]=ldA(b,mf,0); av[mf][1]=ldA(b,mf,1); } \
    _Pragma("unroll") for (int nf = 0; nf < 2; ++nf){ b0v[nf][0]=ldB(b,nf,0); b0v[nf][1]=ldB(b,nf,1); } \
    if (t+1 < T) STAGE(0, b^1, 1, t+1); \
    PH_OPEN(); MF16(0,0,b0v); PH_CLOSE(); \
    _Pragma("unroll") for (int nf = 0; nf < 2; ++nf){ b1v[nf][0]=ldB(b,2+nf,0); b1v[nf][1]=ldB(b,2+nf,1); } \
    if (t+1 < T) STAGE(1, b^1, 0, t+1); \
    PH_OPEN(); MF16(0,2,b1v); PH_CLOSE(); \
    _Pragma("unroll") for (int mf = 0; mf < 4; ++mf){ av[mf][0]=ldA(b,4+mf,0); av[mf][1]=ldA(b,4+mf,1); } \
    if (t+2 < T) STAGE(0, b, 0, t+2); \
    PH_OPEN(); MF16(4,2,b1v); PH_CLOSE(); \
    if (t+2 < T) STAGE(1, b, 1, t+2); \
    PH_OPEN(); MF16(4,0,b0v); \
    __builtin_amdgcn_s_setprio(0); \
    if (t+2 < T) { asm volatile("s_waitcnt vmcnt(4)" ::: "memory"); } \
    else         { asm volatile("s_waitcnt vmcnt(0)" ::: "memory"); } \
    asm volatile("s_barrier" ::: "memory"); \
  }

template<int T>   // K = T*64, T even
__global__ __launch_bounds__(512, 2)
void k_gemm256(const unsigned short* __restrict__ A,
               const unsigned short* __restrict__ B,
               const float* __restrict__ bias,
               float* __restrict__ C,
               int N, int K, int nbn)
{
  __shared__ __align__(1024) char lds8[131072];
  const int tid = threadIdx.x;
  const int ln = tid & 63, wv = tid >> 6;
  const int wm = wv >> 2, wn = wv & 3;
  const int llo = ln & 15, lhi = ln >> 4;

  const int nwg = gridDim.x;
  const int cpx = nwg >> 3;
  const int bid = blockIdx.x;
  const int swz = (bid & 7) * cpx + (bid >> 3);
  const int bm = swz / nbn, bn = swz % nbn;
  const int m0 = bm * 256, n0 = bn * 256;

  const int srow = tid >> 3;
  const int sslot = (tid & 7) ^ (srow & 7);
  const unsigned short* Abase = A + (size_t)(m0 + srow) * K + sslot * 8;
  const unsigned short* Bbase = B + (size_t)(n0 + srow) * K + sslot * 8;
  const size_t rowK64 = (size_t)64 * K;
  char* ldsWaveDst = lds8 + (wv << 10);

  const int swz0 = ((lhi ^ (ln & 7)) << 4);
  const char* aRd0 = lds8 + (wm*64 + llo)*128 + swz0;
  const char* aRd1 = lds8 + (wm*64 + llo)*128 + (swz0 ^ 64);
  const char* bRd0 = lds8 + 65536 + (wn*32 + llo)*128 + swz0;
  const char* bRd1 = lds8 + 65536 + (wn*32 + llo)*128 + (swz0 ^ 64);

  auto ldA = [&](int b, int mf, int ks) -> short8 {
    const char* p = (ks ? aRd1 : aRd0) + b*32768 + (mf>>2)*16384 + (mf&3)*2048;
    return *reinterpret_cast<const short8*>(p);
  };
  auto ldB = [&](int b, int nf, int ks) -> short8 {
    const char* p = (ks ? bRd1 : bRd0) + b*32768 + (nf>>1)*16384 + (nf&1)*2048;
    return *reinterpret_cast<const short8*>(p);
  };

  f32x4 acc[8][4];
  #pragma unroll
  for (int m = 0; m < 8; ++m)
    #pragma unroll
    for (int n = 0; n < 4; ++n) acc[m][n] = 0.0f;

  STAGE(0, 0, 0, 0);
  STAGE(1, 0, 1, 0);
  STAGE(0, 0, 1, 0);
  STAGE(1, 0, 0, 0);
  STAGE(0, 1, 0, 1);
  STAGE(1, 1, 1, 1);
  asm volatile("s_waitcnt vmcnt(4)" ::: "memory");
  asm volatile("s_barrier" ::: "memory");

  short8 av[4][2], b0v[2][2], b1v[2][2];
  #pragma unroll 1
  for (int t0 = 0; t0 < T; t0 += 2){
    TILE(t0,   0);
    TILE(t0+1, 1);
  }

  asm volatile("s_nop 7\n\ts_nop 7\n\ts_nop 7" ::: );

  #pragma unroll
  for (int mf = 0; mf < 8; ++mf){
    const int row = m0 + (mf>>2)*128 + wm*64 + (mf&3)*16 + lhi*4;
    #pragma unroll
    for (int j = 0; j < 4; ++j){
      #pragma unroll
      for (int nf = 0; nf < 4; ++nf){
        const int col = n0 + (nf>>1)*128 + wn*32 + (nf&1)*16 + llo;
        C[(size_t)(row + j) * N + col] = acc[mf][nf][j] + bias[col];
      }
    }
  }
}

// ---------- depthwise 3x3 SAME conv over 32x32 + bias + exact GELU ----------
__global__ void k_dwgelu(const float* __restrict__ t1, const float* __restrict__ dww,
                         const float* __restrict__ dwb, unsigned short* __restrict__ t2)
{
  int idx = blockIdx.x * blockDim.x + threadIdx.x;
  int hq = idx & 31; int t = idx >> 5;
  int h = hq * 4;
  int n = t & (NT-1); int b = t >> 10;
  int y = n >> 5, x = n & 31;

  float w[4][9];
  #pragma unroll
  for (int i = 0; i < 4; ++i)
    #pragma unroll
    for (int k = 0; k < 9; ++k) w[i][k] = dww[(h+i)*9 + k];

  float a0 = dwb[h+0], a1 = dwb[h+1], a2 = dwb[h+2], a3 = dwb[h+3];
  #pragma unroll
  for (int dy = -1; dy <= 1; ++dy){
    int yy = y + dy; if ((unsigned)yy >= 32u) continue;
    #pragma unroll
    for (int dx = -1; dx <= 1; ++dx){
      int xx = x + dx; if ((unsigned)xx >= 32u) continue;
      float4 v = *reinterpret_cast<const float4*>(&t1[((size_t)b*NT + yy*32 + xx)*HIDN + h]);
      int k = (dy+1)*3 + (dx+1);
      a0 += v.x * w[0][k]; a1 += v.y * w[1][k]; a2 += v.z * w[2][k]; a3 += v.w * w[3][k];
    }
  }
  const float is2 = 0.70710678118654752440f;
  a0 = 0.5f*a0*(1.0f + erff(a0*is2));
  a1 = 0.5f*a1*(1.0f + erff(a1*is2));
  a2 = 0.5f*a2*(1.0f + erff(a2*is2));
  a3 = 0.5f*a3*(1.0f + erff(a3*is2));
  ushort4 o; o.x = f2bf(a0); o.y = f2bf(a1); o.z = f2bf(a2); o.w = f2bf(a3);
  *reinterpret_cast<ushort4*>(&t2[(size_t)t*HIDN + h]) = o;
}

// ---------- threefry2x32 (JAX), 20 rounds ----------
__device__ __forceinline__ void threefry(unsigned k0, unsigned k1, unsigned x0, unsigned x1,
                                         unsigned& o0, unsigned& o1){
  unsigned ks2 = k0 ^ k1 ^ 0x1BD11BDAu;
  x0 += k0; x1 += k1;
#define TFR(r) { x0 += x1; x1 = (x1 << r) | (x1 >> (32 - r)); x1 ^= x0; }
  TFR(13) TFR(15) TFR(26) TFR(6)  x0 += k1;  x1 += ks2 + 1u;
  TFR(17) TFR(29) TFR(16) TFR(24) x0 += ks2; x1 += k0 + 2u;
  TFR(13) TFR(15) TFR(26) TFR(6)  x0 += k0;  x1 += k1 + 3u;
  TFR(17) TFR(29) TFR(16) TFR(24) x0 += k1;  x1 += ks2 + 4u;
  TFR(13) TFR(15) TFR(26) TFR(6)  x0 += ks2; x1 += k0 + 5u;
#undef TFR
  o0 = x0; o1 = x1;
}

__device__ __forceinline__ float gumbel_from_bits(unsigned bits){
  float f = __uint_as_float((bits >> 9) | 0x3F800000u) - 1.0f;
  const float TINY = 1.17549435e-38f;
  float u = fmaxf(TINY, f + TINY);
  return -logf(-logf(u));
}

// ---------- csim finalize + min/max normalize + router MLP + gumbel softmax ----------
__global__ void k_router(const float* __restrict__ part, const float* __restrict__ n1sq,
                         const float* __restrict__ r1w, const float* __restrict__ r1b,
                         const float* __restrict__ r2w, const float* __restrict__ r2b,
                         float* __restrict__ out)
{
  int b = blockIdx.x, tid = threadIdx.x;
  __shared__ float cs[NT];
  __shared__ float red[8];
  float n1 = sqrtf(n1sq[b]);
  float lmin = 3.4e38f, lmax = -3.4e38f;
  #pragma unroll
  for (int j = 0; j < 4; ++j){
    int tk = tid + j*256;
    const float* pp = part + (size_t)(b*NT + tk) * 24;
    float dot = 0.f, q = 0.f;
    #pragma unroll
    for (int i = 0; i < 12; ++i){ dot += pp[2*i]; q += pp[2*i + 1]; }
    float v = dot / (n1 * sqrtf(q));
    cs[tk] = v;
    lmin = fminf(lmin, v); lmax = fmaxf(lmax, v);
  }
  int ln = tid & 63, wv = tid >> 6;
  for (int off = 32; off; off >>= 1){
    lmin = fminf(lmin, __shfl_down(lmin, off, 64));
    lmax = fmaxf(lmax, __shfl_down(lmax, off, 64));
  }
  if (ln == 0){ red[wv] = lmin; red[4+wv] = lmax; }
  __syncthreads();
  float mn = fminf(fminf(red[0], red[1]), fminf(red[2], red[3]));
  float mx = fmaxf(fmaxf(red[4], red[5]), fmaxf(red[6], red[7]));
  float rng = mx - mn;
  bool nz = (rng != 0.0f);

  #pragma unroll
  for (int j = 0; j < 4; ++j){
    int tk = tid + j*256;
    float c0 = cs[tk];
    float v = nz ? (c0 - mn) / rng : c0;
    float l0 = r2b[0], l1 = r2b[1];
    for (int k = 0; k < HIDN; ++k){
      float hh = fmaxf(v * r1w[k] + r1b[k], 0.f);
      l0 += hh * r2w[k];
      l1 += hh * r2w[HIDN + k];
    }
    l0 = 1.f / (1.f + expf(-l0));
    l1 = 1.f / (1.f + expf(-l1));
    int t = b*NT + tk;
    unsigned o0, o1;
    threefry(0u, 42u, 0u, (unsigned)(2*t),     o0, o1);
    float g0 = gumbel_from_bits(o0 ^ o1);
    threefry(0u, 42u, 0u, (unsigned)(2*t + 1), o0, o1);
    float g1 = gumbel_from_bits(o0 ^ o1);
    out[t] = 1.f / (1.f + expf((l1 + g1) - (l0 + g0)));
  }
}

extern "C" void kernel_launch(void* const* d_in, const int* in_sizes, int n_in,
                              void* d_out, int out_size, void* d_ws, size_t ws_size,
                              hipStream_t stream)
{
  (void)in_sizes; (void)n_in; (void)out_size;
  const float* input  = (const float*)d_in[0];
  const float* input2 = (const float*)d_in[3];
  const float* qkv_w  = (const float*)d_in[4];
  const float* qkv_b  = (const float*)d_in[5];
  const float* fc1_w  = (const float*)d_in[6];
  const float* fc1_b  = (const float*)d_in[7];
  const float* dw_w   = (const float*)d_in[8];
  const float* dw_b   = (const float*)d_in[9];
  const float* fc2_w  = (const float*)d_in[10];
  const float* fc2_b  = (const float*)d_in[11];
  const float* r1_w   = (const float*)d_in[12];
  const float* r1_b   = (const float*)d_in[13];
  const float* r2_w   = (const float*)d_in[14];
  const float* r2_b   = (const float*)d_in[15];

  float* q1 = (float*)d_out;
  float* router = q1 + (size_t)2 * MTOT * OUTF;

  if (ws_size < 67000000u) return;

  char* ws = (char*)d_ws;
  unsigned short* x1b = (unsigned short*)ws; ws += (size_t)MTOT*CH*2;   // input bf16   } contiguous:
  unsigned short* xrb = (unsigned short*)ws; ws += (size_t)MTOT*CH*2;   // refine bf16  } A=[x1b;xrb]
  unsigned short* wqb = (unsigned short*)ws; ws += (size_t)OUTF*CH*2;
  unsigned short* w1b = (unsigned short*)ws; ws += (size_t)HIDN*CH*2;
  unsigned short* w2b = (unsigned short*)ws; ws += (size_t)CH*HIDN*2;
  float*          t1  = (float*)ws;          ws += (size_t)MTOT*HIDN*4; // fc1 out; dead after dwgelu
  unsigned short* t2  = (unsigned short*)ws; ws += (size_t)MTOT*HIDN*2;
  float*          mb  = (float*)ws;          ws += (size_t)BQ*CH*4;
  float*          n1sq= (float*)ws;          ws += 256;
  float*          part= t1;                  // csim partials [16384][6][2][2] alias dead t1

  // one fused convert for all 5 tensors (27131904 elems / 4 / 256 = 26496 blocks)
  k_f2bf_all<<<dim3(26496), 256, 0, stream>>>(
      input, input2, qkv_w, fc1_w, fc2_w, x1b, xrb, wqb, w1b, w2b);

  hipMemsetAsync(n1sq, 0, 64, stream);
  k_mean<<<dim3(BQ, 6), 256, 0, stream>>>(input, mb, n1sq);

  // fc1: [16384,768] x [128,768]^T -> t1 f32
  k_gemm<0><<<dim3(MTOT/128, HIDN/128), 256, 0, stream>>>(
      xrb, w1b, fc1_b, nullptr, t1, nullptr, nullptr, nullptr, MTOT, HIDN, CH);
  // depthwise conv + gelu -> t2 bf16
  k_dwgelu<<<dim3(MTOT*32/256), 256, 0, stream>>>(t1, dw_w, dw_b, t2);
  // fc2 + input2(bf16) add -> refine bf16 (into xrb) + csim partials -> part
  k_gemm<1><<<dim3(MTOT/128, CH/128), 256, 0, stream>>>(
      t2, w2b, fc2_b, xrb, nullptr, xrb, mb, part, MTOT, CH, HIDN);

  // combined qkv: [q1;q2] = [input;refine] @ qkv_w^T + b  (M = 32768)
  k_gemm256<CH/64><<<dim3((2*MTOT/256) * (OUTF/256)), 512, 0, stream>>>(
      x1b, wqb, qkv_b, q1, OUTF, CH, OUTF/256);

  k_router<<<dim3(BQ), 256, 0, stream>>>(part, n1sq, r1_w, r1_b, r2_w, r2_b, router);
}